// Round 6
// baseline (451.972 us; speedup 1.0000x reference)
//
#include <hip/hip_runtime.h>

typedef __bf16 bf16x8 __attribute__((ext_vector_type(8)));
typedef float  f32x2  __attribute__((ext_vector_type(2)));
typedef float  f32x4  __attribute__((ext_vector_type(4)));
typedef float  f32x16 __attribute__((ext_vector_type(16)));

constexpr int M_ROWS = 65536;
constexpr int N_COLS = 2048;
constexpr int K_DIM  = 512;
constexpr int BM = 128, BN = 128, BK = 32;
constexpr int NKT = K_DIM / BK;        // 16 K-steps
constexpr int MB_CNT = M_ROWS / BM;    // 512
constexpr int NB_CNT = N_COLS / BN;    // 16

constexpr size_t A_ELEMS = (size_t)M_ROWS * K_DIM;
constexpr size_t W_ELEMS = (size_t)N_COLS * K_DIM;
// packed blocks per (tile, kt): [hi 4096 ushorts][lo 4096 ushorts] = 16 KB
constexpr size_t APK_USHORTS = (size_t)MB_CNT * NKT * 8192;  // 128 MiB
constexpr size_t WPK_USHORTS = (size_t)NB_CNT * NKT * 8192;  //   4 MiB

__device__ __forceinline__ unsigned short f2bf(float f){
  unsigned int u = __float_as_uint(f);
  u += 0x7FFFu + ((u >> 16) & 1u);     // RNE
  return (unsigned short)(u >> 16);
}
__device__ __forceinline__ float bf2f(unsigned short h){
  return __uint_as_float(((unsigned int)h) << 16);
}
__device__ __forceinline__ void split4(const float4& v, ushort4& h, ushort4& l){
  h.x = f2bf(v.x); l.x = f2bf(v.x - bf2f(h.x));
  h.y = f2bf(v.y); l.y = f2bf(v.y - bf2f(h.y));
  h.z = f2bf(v.z); l.z = f2bf(v.z - bf2f(h.z));
  h.w = f2bf(v.w); l.w = f2bf(v.w - bf2f(h.w));
}
__device__ __forceinline__ void split4v(const f32x4& v, ushort4& h, ushort4& l){
  h.x = f2bf(v.x); l.x = f2bf(v.x - bf2f(h.x));
  h.y = f2bf(v.y); l.y = f2bf(v.y - bf2f(h.y));
  h.z = f2bf(v.z); l.z = f2bf(v.z - bf2f(h.z));
  h.w = f2bf(v.w); l.w = f2bf(v.w - bf2f(h.w));
}

__device__ __forceinline__ void gl_lds16(const void* g, void* l){
  __builtin_amdgcn_global_load_lds(
      (const __attribute__((address_space(1))) unsigned int*)g,
      (__attribute__((address_space(3))) unsigned int*)l, 16, 0, 0);
}

constexpr float INV2PI = 0.15915494309189535f;
__device__ __forceinline__ float cos_scaled(float v){
  float rev = v * INV2PI;
  rev -= floorf(rev);                   // [0,1) revolutions for v_cos
  return 0.03125f * __builtin_amdgcn_cosf(rev);
}

// ============ fused prepass: X->Apk (8192 blocks) + W->Wpk (1024) ===========
// 32x32x16 fragment layout. A operand: lane = h*32 + (m&31), holds 8 k-contig
// bf16 at k = ks*16 + h*8 (h = lane>>5). Apk chunk c = (rb*2+ks)*64 + lane,
// rb = row>>5.  B operand symmetric in cols, with col-perm: frag (gidx=wn*2+j,
// ks), lane = h*32 + fc  holds actual col wn*64 + fc*2 + j.
__global__ void pack_fused(const float* __restrict__ X, const float* __restrict__ W,
                           unsigned short* __restrict__ Apk,
                           unsigned short* __restrict__ Wpk){
  __shared__ __align__(16) unsigned short lds[8192];
  const int b = blockIdx.x, t = threadIdx.x;
  if (b < MB_CNT * NKT){
    const int mb = b >> 4, kt = b & 15;
    const float* src = X + (size_t)mb * 128 * K_DIM + kt * 32;
    const int fq = t & 7, r0 = t >> 3;      // fq: which 4-float k-chunk
    const int ks = fq >> 2;                  // k-slice of 16
    const int h  = (fq >> 1) & 1;           // lane-half (k-group of 8)
    const int ko = (fq & 1) * 4;             // elem offset within 8
    #pragma unroll
    for (int it = 0; it < 4; ++it){
      int row = r0 + it * 32;
      f32x4 v = __builtin_nontemporal_load(
          reinterpret_cast<const f32x4*>(src + (size_t)row * K_DIM + fq * 4));
      ushort4 hh, ll; split4v(v, hh, ll);
      int rb = row >> 5, lane = h * 32 + (row & 31);
      int base = ((rb * 2 + ks) * 64 + lane) * 8 + ko;
      *reinterpret_cast<ushort4*>(lds + base)        = hh;
      *reinterpret_cast<ushort4*>(lds + 4096 + base) = ll;
    }
    __syncthreads();
    unsigned short* dst = Apk + ((size_t)mb * NKT + kt) * 8192;
    #pragma unroll
    for (int it = 0; it < 4; ++it){
      int c = t + it * 256;
      *reinterpret_cast<int4*>(dst + c * 8) = *reinterpret_cast<const int4*>(lds + c * 8);
    }
  } else {
    // W patch: 32 cols x 32 k.  b2 -> (nbx, kt): n0 = nbx*32, k0 = kt*32.
    const int b2 = b - MB_CNT * NKT;
    const int nbx = b2 & 63, kt = b2 >> 6;
    const int n0 = nbx * 32;
    const int nb = nbx >> 2;                 // 128-col Wpk block
    float (*tf)[33] = reinterpret_cast<float(*)[33]>(lds);
    int tx = t & 31, ty = t >> 5;
    #pragma unroll
    for (int rr = 0; rr < 4; ++rr)
      tf[ty + rr*8][tx] = W[(size_t)(kt * 32 + ty + rr*8) * N_COLS + n0 + tx];
    __syncthreads();
    unsigned short* dst = Wpk + ((size_t)nb * NKT + kt) * 8192;
    const int ks = tx >> 4, kk = tx & 15;
    const int h2 = kk >> 3, ko = kk & 7;
    #pragma unroll
    for (int rr = 0; rr < 4; ++rr){
      int nl = ty + rr*8;                    // local col 0..31
      float vv = tf[tx][nl];                 // W[k0+tx][n0+nl]
      unsigned short hh = f2bf(vv);
      unsigned short ll = f2bf(vv - bf2f(hh));
      int ng = (nbx & 3) * 32 + nl;          // col within 128-block
      int wn = ng >> 6, gg = ng & 63;
      int j = gg & 1, fc = gg >> 1;
      int e = (((wn*2 + j)*2 + ks) * 64 + h2*32 + fc) * 8 + ko;
      dst[e] = hh; dst[4096 + e] = ll;
    }
  }
}

// ============ main GEMM + cos epilogue (32x32x16 MFMA) ======================
// LDS 48 KB: Abuf0 @0, Abuf1 @16K, Bbuf @32K (each [hi 8K|lo 8K] bytes).
// Per K-step: 16 ds_read_b128 -> bar1 -> issue 8 gl_lds(kt+1) -> 24 MFMA -> bar2.
__launch_bounds__(256, 2)
__global__ void rbf_gemm_pk(const unsigned short* __restrict__ Apk,
                            const unsigned short* __restrict__ Wpk,
                            const float* __restrict__ bvec,
                            float* __restrict__ out){
  __shared__ __align__(16) unsigned short smem[24576];   // 48 KB

  int orig = blockIdx.x;                       // 8192 blocks, 8192 % 8 == 0
  int wgid = (orig & 7) * 1024 + (orig >> 3);  // bijective XCD swizzle
  int mb = wgid >> 4, nb = wgid & 15;
  int m0 = mb * BM, n0 = nb * BN;

  int tid = threadIdx.x, lane = tid & 63, wid = tid >> 6;
  int wm = wid >> 1, wn = wid & 1;

  const char* asrc = (const char*)(Apk + (size_t)mb * NKT * 8192) + tid * 16;
  const char* bsrc = (const char*)(Wpk + (size_t)nb * NKT * 8192) + tid * 16;
  char* ldsb = (char*)smem;
  const int ldst = wid * 1024;                 // per-wave dest offset per 4KB sec

  f32x16 acc[2][2];
  #pragma unroll
  for (int i = 0; i < 2; ++i)
    #pragma unroll
    for (int j = 0; j < 2; ++j)
      #pragma unroll
      for (int m = 0; m < 16; ++m) acc[i][j][m] = 0.f;

  // prologue: stage tile 0 (A -> Abuf0, B -> Bbuf)
  #pragma unroll
  for (int it = 0; it < 4; ++it)
    gl_lds16(asrc + it * 4096, ldsb + it * 4096 + ldst);
  #pragma unroll
  for (int it = 0; it < 4; ++it)
    gl_lds16(bsrc + it * 4096, ldsb + 32768 + it * 4096 + ldst);
  __syncthreads();                             // drain: tile 0 ready

  #pragma unroll 1
  for (int kt = 0; kt < NKT; ++kt){
    const unsigned short* SA = smem + (kt & 1) * 8192;   // ushort idx
    const unsigned short* SB = smem + 16384;

    // 1) ds_read current-tile fragments (lane-linear, conflict-free)
    bf16x8 ah[2][2], al[2][2], bh[2][2], bl[2][2];
    #pragma unroll
    for (int i = 0; i < 2; ++i)
      #pragma unroll
      for (int ks = 0; ks < 2; ++ks){
        int o = (((wm*2 + i)*2 + ks) * 64 + lane) * 8;
        ah[i][ks] = *reinterpret_cast<const bf16x8*>(&SA[o]);
        al[i][ks] = *reinterpret_cast<const bf16x8*>(&SA[o + 4096]);
      }
    #pragma unroll
    for (int j = 0; j < 2; ++j)
      #pragma unroll
      for (int ks = 0; ks < 2; ++ks){
        int o = (((wn*2 + j)*2 + ks) * 64 + lane) * 8;
        bh[j][ks] = *reinterpret_cast<const bf16x8*>(&SB[o]);
        bl[j][ks] = *reinterpret_cast<const bf16x8*>(&SB[o + 4096]);
      }
    __syncthreads();   // bar1: all waves done reading (lgkm drained by compiler)

    // 2) issue next-tile gl_lds EARLY (in flight across the MFMA cluster)
    if (kt + 1 < NKT){
      char* LA = ldsb + ((kt + 1) & 1) * 16384;
      const char* ab = asrc + (size_t)(kt + 1) * 16384;
      const char* bb = bsrc + (size_t)(kt + 1) * 16384;
      #pragma unroll
      for (int it = 0; it < 4; ++it) gl_lds16(ab + it * 4096, LA + it * 4096 + ldst);
      #pragma unroll
      for (int it = 0; it < 4; ++it) gl_lds16(bb + it * 4096, ldsb + 32768 + it * 4096 + ldst);
    }

    // 3) MFMA cluster: 24 x 32x32x16
    #pragma unroll
    for (int i = 0; i < 2; ++i){
      #pragma unroll
      for (int j = 0; j < 2; ++j){
        #pragma unroll
        for (int ks = 0; ks < 2; ++ks){
          acc[i][j] = __builtin_amdgcn_mfma_f32_32x32x16_bf16(ah[i][ks], bh[j][ks], acc[i][j], 0, 0, 0);
          acc[i][j] = __builtin_amdgcn_mfma_f32_32x32x16_bf16(al[i][ks], bh[j][ks], acc[i][j], 0, 0, 0);
          acc[i][j] = __builtin_amdgcn_mfma_f32_32x32x16_bf16(ah[i][ks], bl[j][ks], acc[i][j], 0, 0, 0);
        }
      }
    }

    __syncthreads();   // bar2: vmcnt drain (covered by MFMA) — next tile ready
  }

  // epilogue: C/D 32x32 layout col=lane&31, row=(m&3)+8*(m>>2)+4*(lane>>5).
  // col-perm: frag j, frag-col cf -> actual col n0 + wn*64 + cf*2 + j
  // -> per (i,m): float2 {acc[i][0][m], acc[i][1][m]} nontemporal store.
  int cf = lane & 31, h = lane >> 5;
  int colb = n0 + wn * 64 + cf * 2;
  f32x2 bv = *reinterpret_cast<const f32x2*>(bvec + colb);
  #pragma unroll
  for (int i = 0; i < 2; ++i){
    #pragma unroll
    for (int m = 0; m < 16; ++m){
      int rl = (m & 3) + 8 * (m >> 2) + 4 * h;
      int row = m0 + wm * 64 + i * 32 + rl;
      f32x2 o;
      o.x = cos_scaled(acc[i][0][m] + bv.x);
      o.y = cos_scaled(acc[i][1][m] + bv.y);
      __builtin_nontemporal_store(o, reinterpret_cast<f32x2*>(out + (size_t)row * N_COLS + colb));
    }
  }
}

// ================= fallback (no workspace): 16x16 path ======================
constexpr int LDSK = 40;
constexpr int SEC  = 128 * LDSK;
__launch_bounds__(256, 2)
__global__ void rbf_gemm_nows(const float* __restrict__ X, const float* __restrict__ W,
                              const float* __restrict__ bvec, float* __restrict__ out){
  __shared__ __align__(16) unsigned short smem[4 * SEC];
  int orig = blockIdx.x;
  int wgid = (orig & 7) * (int)(gridDim.x >> 3) + (orig >> 3);
  int mb = wgid >> 4, nb = wgid & 15;
  int m0 = mb * BM, n0 = nb * BN;
  int tid = threadIdx.x, lane = tid & 63, wid = tid >> 6;
  int wm = wid >> 1, wn = wid & 1;
  int r = lane & 15, g = lane >> 4;

  const float* asrc[4]; int alofs[4]; float4 ra[4];
  const float* wsrc[4]; int wnq4[4]; int wkr[4]; float4 rw[4];
  #pragma unroll
  for (int i = 0; i < 4; ++i){
    int c = tid + i * 256;
    int row = c >> 3, q = c & 7;
    asrc[i]  = X + (size_t)(m0 + row) * K_DIM + q * 4;
    alofs[i] = row * LDSK + q * 4;
  }
  #pragma unroll
  for (int i = 0; i < 4; ++i) ra[i] = *reinterpret_cast<const float4*>(asrc[i]);
  #pragma unroll
  for (int i = 0; i < 4; ++i){
    int c = tid + i * 256;
    int kr = c >> 5, nq = c & 31;
    wsrc[i] = W + (size_t)kr * N_COLS + n0 + nq * 4;
    wkr[i] = kr; wnq4[i] = nq * 4;
  }
  #pragma unroll
  for (int i = 0; i < 4; ++i) rw[i] = *reinterpret_cast<const float4*>(wsrc[i]);

  f32x4 acc[4][4];
  f32x4 zero = {0.f, 0.f, 0.f, 0.f};
  #pragma unroll
  for (int i = 0; i < 4; ++i)
    #pragma unroll
    for (int j = 0; j < 4; ++j) acc[i][j] = zero;

  int aoff[4], boff[4];
  #pragma unroll
  for (int i = 0; i < 4; ++i) aoff[i] = (wm*64 + i*16 + r) * LDSK + g * 8;
  #pragma unroll
  for (int j = 0; j < 4; ++j) boff[j] = (wn*64 + j*16 + r) * LDSK + g * 8;

  #pragma unroll 1
  for (int kt = 0; kt < NKT; ++kt){
    __syncthreads();
    #pragma unroll
    for (int i = 0; i < 4; ++i){
      ushort4 h, l;
      split4(ra[i], h, l);
      *reinterpret_cast<ushort4*>(&smem[alofs[i]])       = h;
      *reinterpret_cast<ushort4*>(&smem[SEC + alofs[i]]) = l;
    }
    #pragma unroll
    for (int i = 0; i < 4; ++i){
      float vv[4] = {rw[i].x, rw[i].y, rw[i].z, rw[i].w};
      #pragma unroll
      for (int w2 = 0; w2 < 4; ++w2){
        unsigned short h = f2bf(vv[w2]);
        unsigned short l = f2bf(vv[w2] - bf2f(h));
        int n = wnq4[i] + w2;
        smem[2*SEC + n*LDSK + wkr[i]] = h;
        smem[3*SEC + n*LDSK + wkr[i]] = l;
      }
    }
    if (kt < NKT - 1){
      #pragma unroll
      for (int i = 0; i < 4; ++i)
        ra[i] = *reinterpret_cast<const float4*>(asrc[i] + (kt+1)*BK);
      #pragma unroll
      for (int i = 0; i < 4; ++i)
        rw[i] = *reinterpret_cast<const float4*>(wsrc[i] + (size_t)(kt+1)*BK*N_COLS);
    }
    __syncthreads();
    bf16x8 ah[4], al[4], bh[4], bl[4];
    #pragma unroll
    for (int i = 0; i < 4; ++i){
      ah[i] = *reinterpret_cast<const bf16x8*>(&smem[aoff[i]]);
      al[i] = *reinterpret_cast<const bf16x8*>(&smem[SEC + aoff[i]]);
    }
    #pragma unroll
    for (int j = 0; j < 4; ++j){
      bh[j] = *reinterpret_cast<const bf16x8*>(&smem[2*SEC + boff[j]]);
      bl[j] = *reinterpret_cast<const bf16x8*>(&smem[3*SEC + boff[j]]);
    }
    #pragma unroll
    for (int i = 0; i < 4; ++i){
      #pragma unroll
      for (int j = 0; j < 4; ++j){
        acc[i][j] = __builtin_amdgcn_mfma_f32_16x16x32_bf16(ah[i], bh[j], acc[i][j], 0, 0, 0);
        acc[i][j] = __builtin_amdgcn_mfma_f32_16x16x32_bf16(al[i], bh[j], acc[i][j], 0, 0, 0);
        acc[i][j] = __builtin_amdgcn_mfma_f32_16x16x32_bf16(ah[i], bl[j], acc[i][j], 0, 0, 0);
      }
    }
  }

  float bvv[4];
  #pragma unroll
  for (int j = 0; j < 4; ++j) bvv[j] = bvec[n0 + wn*64 + j*16 + r];
  #pragma unroll
  for (int i = 0; i < 4; ++i){
    #pragma unroll
    for (int j = 0; j < 4; ++j){
      int col = n0 + wn*64 + j*16 + r;
      #pragma unroll
      for (int p = 0; p < 4; ++p){
        int row = m0 + wm*64 + i*16 + g*4 + p;
        out[(size_t)row * N_COLS + col] = cos_scaled(acc[i][j][p] + bvv[j]);
      }
    }
  }
}

extern "C" void kernel_launch(void* const* d_in, const int* in_sizes, int n_in,
                              void* d_out, int out_size, void* d_ws, size_t ws_size,
                              hipStream_t stream){
  const float* X = (const float*)d_in[0];
  const float* W = (const float*)d_in[1];
  const float* b = (const float*)d_in[2];
  float* out = (float*)d_out;
  unsigned short* ws = (unsigned short*)d_ws;

  const size_t needP = (APK_USHORTS + WPK_USHORTS) * sizeof(unsigned short); // 132 MiB

  if (ws && ws_size >= needP){
    unsigned short* Apk = ws;
    unsigned short* Wpk = ws + APK_USHORTS;
    pack_fused<<<MB_CNT * NKT + 64 * NKT, 256, 0, stream>>>(X, W, Apk, Wpk);
    rbf_gemm_pk<<<8192, 256, 0, stream>>>(Apk, Wpk, b, out);
  } else {
    rbf_gemm_nows<<<8192, 256, 0, stream>>>(X, W, b, out);
  }
}

// Round 7
// 394.505 us; speedup vs baseline: 1.1457x; 1.1457x over previous
//
#include <hip/hip_runtime.h>

typedef __bf16 bf16x8 __attribute__((ext_vector_type(8)));
typedef float  f32x4  __attribute__((ext_vector_type(4)));

constexpr int M_ROWS = 65536;
constexpr int N_COLS = 2048;
constexpr int K_DIM  = 512;
constexpr int BM = 128, BN = 128, BK = 32;
constexpr int NKT = K_DIM / BK;        // 16 K-steps
constexpr int MB_CNT = M_ROWS / BM;    // 512
constexpr int NB_CNT = N_COLS / BN;    // 16

constexpr size_t A_ELEMS = (size_t)M_ROWS * K_DIM;
constexpr size_t W_ELEMS = (size_t)N_COLS * K_DIM;
// packed blocks per (tile, kt): [hi 4096 ushorts][lo 4096 ushorts] = 16 KB
constexpr size_t APK_USHORTS = (size_t)MB_CNT * NKT * 8192;  // 128 MiB
constexpr size_t WPK_USHORTS = (size_t)NB_CNT * NKT * 8192;  //   4 MiB

__device__ __forceinline__ unsigned short f2bf(float f){
  unsigned int u = __float_as_uint(f);
  u += 0x7FFFu + ((u >> 16) & 1u);     // RNE
  return (unsigned short)(u >> 16);
}
__device__ __forceinline__ float bf2f(unsigned short h){
  return __uint_as_float(((unsigned int)h) << 16);
}
__device__ __forceinline__ void split4(const float4& v, ushort4& h, ushort4& l){
  h.x = f2bf(v.x); l.x = f2bf(v.x - bf2f(h.x));
  h.y = f2bf(v.y); l.y = f2bf(v.y - bf2f(h.y));
  h.z = f2bf(v.z); l.z = f2bf(v.z - bf2f(h.z));
  h.w = f2bf(v.w); l.w = f2bf(v.w - bf2f(h.w));
}
__device__ __forceinline__ void split4v(const f32x4& v, ushort4& h, ushort4& l){
  h.x = f2bf(v.x); l.x = f2bf(v.x - bf2f(h.x));
  h.y = f2bf(v.y); l.y = f2bf(v.y - bf2f(h.y));
  h.z = f2bf(v.z); l.z = f2bf(v.z - bf2f(h.z));
  h.w = f2bf(v.w); l.w = f2bf(v.w - bf2f(h.w));
}

__device__ __forceinline__ void gl_lds16(const void* g, void* l){
  __builtin_amdgcn_global_load_lds(
      (const __attribute__((address_space(1))) unsigned int*)g,
      (__attribute__((address_space(3))) unsigned int*)l, 16, 0, 0);
}

constexpr float INV2PI = 0.15915494309189535f;
__device__ __forceinline__ float cos_scaled(float v){
  float rev = v * INV2PI;
  rev -= floorf(rev);                   // [0,1) revolutions for v_cos
  return 0.03125f * __builtin_amdgcn_cosf(rev);
}

// ============ fused prepass: X->Apk (8192 blocks) + W->Wpk (1024) ===========
// 16x16x32 fragment layout.
// Apk block (mb,kt): chunk c = i*64 + q*16 + r  <->  A row mb*128+i*16+r,
// k = kt*32 + q*8..+7 (k-contiguous bf16). hi at +0, lo at +4096 ushorts.
// Wpk block (nb,kt): chunk c = j*64 + q*16 + fc holds W[k=kt*32+q*8..][n],
// n = nb*128 + fc*8 + j  (col-perm: lane fc owns 8 consecutive output cols).
__global__ void pack_fused(const float* __restrict__ X, const float* __restrict__ W,
                           unsigned short* __restrict__ Apk,
                           unsigned short* __restrict__ Wpk){
  __shared__ __align__(16) unsigned short lds[8192];
  const int b = blockIdx.x, t = threadIdx.x;
  if (b < MB_CNT * NKT){
    const int mb = b >> 4, kt = b & 15;
    const float* src = X + (size_t)mb * 128 * K_DIM + kt * 32;
    const int fq = t & 7, r0 = t >> 3;
    #pragma unroll
    for (int it = 0; it < 4; ++it){
      int row = r0 + it * 32;
      f32x4 v = __builtin_nontemporal_load(
          reinterpret_cast<const f32x4*>(src + (size_t)row * K_DIM + fq * 4));
      ushort4 h, l; split4v(v, h, l);
      int i = row >> 4, r = row & 15, q = fq >> 1, half = fq & 1;
      int base = (i * 64 + q * 16 + r) * 8 + half * 4;
      *reinterpret_cast<ushort4*>(lds + base)        = h;
      *reinterpret_cast<ushort4*>(lds + 4096 + base) = l;
    }
    __syncthreads();
    unsigned short* dst = Apk + ((size_t)mb * NKT + kt) * 8192;
    #pragma unroll
    for (int it = 0; it < 4; ++it){
      int c = t + it * 256;
      *reinterpret_cast<int4*>(dst + c * 8) = *reinterpret_cast<const int4*>(lds + c * 8);
    }
  } else {
    // W patch: 32 cols x 32 k.  n0 = nbx*32, k0 = kt*32.
    const int b2 = b - MB_CNT * NKT;
    const int nbx = b2 & 63, kt = b2 >> 6;
    const int n0 = nbx * 32;
    const int nb = nbx >> 2;                 // 128-col Wpk block
    float (*tf)[33] = reinterpret_cast<float(*)[33]>(lds);
    int tx = t & 31, ty = t >> 5;
    #pragma unroll
    for (int rr = 0; rr < 4; ++rr)
      tf[ty + rr*8][tx] = W[(size_t)(kt * 32 + ty + rr*8) * N_COLS + n0 + tx];
    __syncthreads();
    unsigned short* dst = Wpk + ((size_t)nb * NKT + kt) * 8192;
    const int q = tx >> 3, ko = tx & 7;
    #pragma unroll
    for (int rr = 0; rr < 4; ++rr){
      int nl = ty + rr*8;                    // local col 0..31
      float vv = tf[tx][nl];                 // W[k0+tx][n0+nl]
      unsigned short hh = f2bf(vv);
      unsigned short ll = f2bf(vv - bf2f(hh));
      int ng = (nbx & 3) * 32 + nl;          // col within 128-block
      int j = ng & 7, fc = ng >> 3;          // col-perm: ng = fc*8 + j
      int e = (j * 64 + q * 16 + fc) * 8 + ko;
      dst[e] = hh; dst[4096 + e] = ll;
    }
  }
}

// ============ main GEMM + cos epilogue ======================================
// 4x1 waves: wave wid owns rows [wid*32, wid*32+32) x all 128 cols.
// A: direct per-lane global loads (fragment-linear, no LDS), reg-dbuffed.
// B: LDS dbuf 2x16KB, staged via gl_lds issued at TOP of each step
//    (latency spans the whole step). ONE barrier per K-step.
__launch_bounds__(256, 3)
__global__ void rbf_gemm_d(const unsigned short* __restrict__ Apk,
                           const unsigned short* __restrict__ Wpk,
                           const float* __restrict__ bvec,
                           float* __restrict__ out){
  __shared__ __align__(16) unsigned short smem[2 * 8192];   // 32 KB (B only)

  int orig = blockIdx.x;                       // 8192 blocks, 8192 % 8 == 0
  int wgid = (orig & 7) * 1024 + (orig >> 3);  // bijective XCD swizzle
  int mb = wgid >> 4, nb = wgid & 15;
  int m0 = mb * BM, n0 = nb * BN;

  int tid = threadIdx.x, lane = tid & 63, wid = tid >> 6;
  int r = lane & 15, g = lane >> 4;

  const char* abase = (const char*)(Apk + (size_t)mb * NKT * 8192);
  const char* bbase = (const char*)(Wpk + (size_t)nb * NKT * 8192);
  char* ldsb = (char*)smem;
  const int aoff0 = (wid * 2 + 0) * 1024 + lane * 16;   // byte offset, subtile i=0
  const int aoff1 = (wid * 2 + 1) * 1024 + lane * 16;   // subtile i=1
  const int bsoff = wid * 1024 + lane * 16;             // staging src lane offset
  const int bdoff = wid * 1024;                          // staging dest (wave-uniform)

  f32x4 acc[2][8];
  #pragma unroll
  for (int i = 0; i < 2; ++i)
    #pragma unroll
    for (int j = 0; j < 8; ++j) acc[i][j] = (f32x4){0.f, 0.f, 0.f, 0.f};

  // prologue: A[0] -> regs, B[0] -> buf0
  bf16x8 ahA0, ahA1, alA0, alA1, ahB0, ahB1, alB0, alB1;
  ahA0 = *reinterpret_cast<const bf16x8*>(abase + aoff0);
  ahA1 = *reinterpret_cast<const bf16x8*>(abase + aoff1);
  alA0 = *reinterpret_cast<const bf16x8*>(abase + 8192 + aoff0);
  alA1 = *reinterpret_cast<const bf16x8*>(abase + 8192 + aoff1);
  #pragma unroll
  for (int it = 0; it < 4; ++it)
    gl_lds16(bbase + it * 4096 + bsoff, ldsb + it * 4096 + bdoff);
  __syncthreads();                             // B[0] ready

  #pragma unroll 1
  for (int kt = 0; kt < NKT; kt += 2){
    // ---------------- even sub-step: parity 0 ----------------
    {
      const unsigned short* SB = smem;                       // buf0
      // issue B[kt+1] -> buf1 at step TOP (covered by whole step)
      {
        const char* bb = bbase + (size_t)(kt + 1) * 16384;
        #pragma unroll
        for (int it = 0; it < 4; ++it)
          gl_lds16(bb + it * 4096 + bsoff, ldsb + 16384 + it * 4096 + bdoff);
      }
      // prefetch A[kt+1] -> regs B-set
      {
        const char* ab = abase + (size_t)(kt + 1) * 16384;
        ahB0 = *reinterpret_cast<const bf16x8*>(ab + aoff0);
        ahB1 = *reinterpret_cast<const bf16x8*>(ab + aoff1);
        alB0 = *reinterpret_cast<const bf16x8*>(ab + 8192 + aoff0);
        alB1 = *reinterpret_cast<const bf16x8*>(ab + 8192 + aoff1);
      }
      #pragma unroll
      for (int j = 0; j < 8; ++j){
        int o = (j * 64 + lane) * 8;
        bf16x8 bh = *reinterpret_cast<const bf16x8*>(&SB[o]);
        bf16x8 bl = *reinterpret_cast<const bf16x8*>(&SB[o + 4096]);
        acc[0][j] = __builtin_amdgcn_mfma_f32_16x16x32_bf16(ahA0, bh, acc[0][j], 0, 0, 0);
        acc[1][j] = __builtin_amdgcn_mfma_f32_16x16x32_bf16(ahA1, bh, acc[1][j], 0, 0, 0);
        acc[0][j] = __builtin_amdgcn_mfma_f32_16x16x32_bf16(alA0, bh, acc[0][j], 0, 0, 0);
        acc[1][j] = __builtin_amdgcn_mfma_f32_16x16x32_bf16(alA1, bh, acc[1][j], 0, 0, 0);
        acc[0][j] = __builtin_amdgcn_mfma_f32_16x16x32_bf16(ahA0, bl, acc[0][j], 0, 0, 0);
        acc[1][j] = __builtin_amdgcn_mfma_f32_16x16x32_bf16(ahA1, bl, acc[1][j], 0, 0, 0);
      }
      __syncthreads();   // drain: B[kt+1] landed; all reads of buf0 done
    }
    // ---------------- odd sub-step: parity 1 -----------------
    {
      const unsigned short* SB = smem + 8192;                // buf1
      if (kt + 2 < NKT){
        const char* bb = bbase + (size_t)(kt + 2) * 16384;
        #pragma unroll
        for (int it = 0; it < 4; ++it)
          gl_lds16(bb + it * 4096 + bsoff, ldsb + it * 4096 + bdoff);
        const char* ab = abase + (size_t)(kt + 2) * 16384;
        ahA0 = *reinterpret_cast<const bf16x8*>(ab + aoff0);
        ahA1 = *reinterpret_cast<const bf16x8*>(ab + aoff1);
        alA0 = *reinterpret_cast<const bf16x8*>(ab + 8192 + aoff0);
        alA1 = *reinterpret_cast<const bf16x8*>(ab + 8192 + aoff1);
      }
      #pragma unroll
      for (int j = 0; j < 8; ++j){
        int o = (j * 64 + lane) * 8;
        bf16x8 bh = *reinterpret_cast<const bf16x8*>(&SB[o]);
        bf16x8 bl = *reinterpret_cast<const bf16x8*>(&SB[o + 4096]);
        acc[0][j] = __builtin_amdgcn_mfma_f32_16x16x32_bf16(ahB0, bh, acc[0][j], 0, 0, 0);
        acc[1][j] = __builtin_amdgcn_mfma_f32_16x16x32_bf16(ahB1, bh, acc[1][j], 0, 0, 0);
        acc[0][j] = __builtin_amdgcn_mfma_f32_16x16x32_bf16(alB0, bh, acc[0][j], 0, 0, 0);
        acc[1][j] = __builtin_amdgcn_mfma_f32_16x16x32_bf16(alB1, bh, acc[1][j], 0, 0, 0);
        acc[0][j] = __builtin_amdgcn_mfma_f32_16x16x32_bf16(ahB0, bl, acc[0][j], 0, 0, 0);
        acc[1][j] = __builtin_amdgcn_mfma_f32_16x16x32_bf16(ahB1, bl, acc[1][j], 0, 0, 0);
      }
      __syncthreads();
    }
  }

  // epilogue: acc[i][j] lane(r,g) reg p -> row m0 + wid*32 + i*16 + g*4 + p,
  // col n0 + r*8 + j  -> two nontemporal float4 stores per (i,p).
  int colb = n0 + r * 8;
  f32x4 bv0 = *reinterpret_cast<const f32x4*>(bvec + colb);
  f32x4 bv1 = *reinterpret_cast<const f32x4*>(bvec + colb + 4);
  #pragma unroll
  for (int i = 0; i < 2; ++i){
    #pragma unroll
    for (int p = 0; p < 4; ++p){
      int row = m0 + wid * 32 + i * 16 + g * 4 + p;
      f32x4 o0, o1;
      o0.x = cos_scaled(acc[i][0][p] + bv0.x);
      o0.y = cos_scaled(acc[i][1][p] + bv0.y);
      o0.z = cos_scaled(acc[i][2][p] + bv0.z);
      o0.w = cos_scaled(acc[i][3][p] + bv0.w);
      o1.x = cos_scaled(acc[i][4][p] + bv1.x);
      o1.y = cos_scaled(acc[i][5][p] + bv1.y);
      o1.z = cos_scaled(acc[i][6][p] + bv1.z);
      o1.w = cos_scaled(acc[i][7][p] + bv1.w);
      float* op = out + (size_t)row * N_COLS + colb;
      __builtin_nontemporal_store(o0, reinterpret_cast<f32x4*>(op));
      __builtin_nontemporal_store(o1, reinterpret_cast<f32x4*>(op + 4));
    }
  }
}

// ================= fallback (no workspace): 16x16 path ======================
constexpr int LDSK = 40;
constexpr int SEC  = 128 * LDSK;
__launch_bounds__(256, 2)
__global__ void rbf_gemm_nows(const float* __restrict__ X, const float* __restrict__ W,
                              const float* __restrict__ bvec, float* __restrict__ out){
  __shared__ __align__(16) unsigned short smem[4 * SEC];
  int orig = blockIdx.x;
  int wgid = (orig & 7) * (int)(gridDim.x >> 3) + (orig >> 3);
  int mb = wgid >> 4, nb = wgid & 15;
  int m0 = mb * BM, n0 = nb * BN;
  int tid = threadIdx.x, lane = tid & 63, wid = tid >> 6;
  int wm = wid >> 1, wn = wid & 1;
  int r = lane & 15, g = lane >> 4;

  const float* asrc[4]; int alofs[4]; float4 ra[4];
  const float* wsrc[4]; int wnq4[4]; int wkr[4]; float4 rw[4];
  #pragma unroll
  for (int i = 0; i < 4; ++i){
    int c = tid + i * 256;
    int row = c >> 3, q = c & 7;
    asrc[i]  = X + (size_t)(m0 + row) * K_DIM + q * 4;
    alofs[i] = row * LDSK + q * 4;
  }
  #pragma unroll
  for (int i = 0; i < 4; ++i) ra[i] = *reinterpret_cast<const float4*>(asrc[i]);
  #pragma unroll
  for (int i = 0; i < 4; ++i){
    int c = tid + i * 256;
    int kr = c >> 5, nq = c & 31;
    wsrc[i] = W + (size_t)kr * N_COLS + n0 + nq * 4;
    wkr[i] = kr; wnq4[i] = nq * 4;
  }
  #pragma unroll
  for (int i = 0; i < 4; ++i) rw[i] = *reinterpret_cast<const float4*>(wsrc[i]);

  f32x4 acc[4][4];
  f32x4 zero = {0.f, 0.f, 0.f, 0.f};
  #pragma unroll
  for (int i = 0; i < 4; ++i)
    #pragma unroll
    for (int j = 0; j < 4; ++j) acc[i][j] = zero;

  int aoff[4], boff[4];
  #pragma unroll
  for (int i = 0; i < 4; ++i) aoff[i] = (wm*64 + i*16 + r) * LDSK + g * 8;
  #pragma unroll
  for (int j = 0; j < 4; ++j) boff[j] = (wn*64 + j*16 + r) * LDSK + g * 8;

  #pragma unroll 1
  for (int kt = 0; kt < NKT; ++kt){
    __syncthreads();
    #pragma unroll
    for (int i = 0; i < 4; ++i){
      ushort4 h, l;
      split4(ra[i], h, l);
      *reinterpret_cast<ushort4*>(&smem[alofs[i]])       = h;
      *reinterpret_cast<ushort4*>(&smem[SEC + alofs[i]]) = l;
    }
    #pragma unroll
    for (int i = 0; i < 4; ++i){
      float vv[4] = {rw[i].x, rw[i].y, rw[i].z, rw[i].w};
      #pragma unroll
      for (int w2 = 0; w2 < 4; ++w2){
        unsigned short h = f2bf(vv[w2]);
        unsigned short l = f2bf(vv[w2] - bf2f(h));
        int n = wnq4[i] + w2;
        smem[2*SEC + n*LDSK + wkr[i]] = h;
        smem[3*SEC + n*LDSK + wkr[i]] = l;
      }
    }
    if (kt < NKT - 1){
      #pragma unroll
      for (int i = 0; i < 4; ++i)
        ra[i] = *reinterpret_cast<const float4*>(asrc[i] + (kt+1)*BK);
      #pragma unroll
      for (int i = 0; i < 4; ++i)
        rw[i] = *reinterpret_cast<const float4*>(wsrc[i] + (size_t)(kt+1)*BK*N_COLS);
    }
    __syncthreads();
    bf16x8 ah[4], al[4], bh[4], bl[4];
    #pragma unroll
    for (int i = 0; i < 4; ++i){
      ah[i] = *reinterpret_cast<const bf16x8*>(&smem[aoff[i]]);
      al[i] = *reinterpret_cast<const bf16x8*>(&smem[SEC + aoff[i]]);
    }
    #pragma unroll
    for (int j = 0; j < 4; ++j){
      bh[j] = *reinterpret_cast<const bf16x8*>(&smem[2*SEC + boff[j]]);
      bl[j] = *reinterpret_cast<const bf16x8*>(&smem[3*SEC + boff[j]]);
    }
    #pragma unroll
    for (int i = 0; i < 4; ++i){
      #pragma unroll
      for (int j = 0; j < 4; ++j){
        acc[i][j] = __builtin_amdgcn_mfma_f32_16x16x32_bf16(ah[i], bh[j], acc[i][j], 0, 0, 0);
        acc[i][j] = __builtin_amdgcn_mfma_f32_16x16x32_bf16(al[i], bh[j], acc[i][j], 0, 0, 0);
        acc[i][j] = __builtin_amdgcn_mfma_f32_16x16x32_bf16(ah[i], bl[j], acc[i][j], 0, 0, 0);
      }
    }
  }

  float bvv[4];
  #pragma unroll
  for (int j = 0; j < 4; ++j) bvv[j] = bvec[n0 + wn*64 + j*16 + r];
  #pragma unroll
  for (int i = 0; i < 4; ++i){
    #pragma unroll
    for (int j = 0; j < 4; ++j){
      int col = n0 + wn*64 + j*16 + r;
      #pragma unroll
      for (int p = 0; p < 4; ++p){
        int row = m0 + wm*64 + i*16 + g*4 + p;
        out[(size_t)row * N_COLS + col] = cos_scaled(acc[i][j][p] + bvv[j]);
      }
    }
  }
}

extern "C" void kernel_launch(void* const* d_in, const int* in_sizes, int n_in,
                              void* d_out, int out_size, void* d_ws, size_t ws_size,
                              hipStream_t stream){
  const float* X = (const float*)d_in[0];
  const float* W = (const float*)d_in[1];
  const float* b = (const float*)d_in[2];
  float* out = (float*)d_out;
  unsigned short* ws = (unsigned short*)d_ws;

  const size_t needP = (APK_USHORTS + WPK_USHORTS) * sizeof(unsigned short); // 132 MiB

  if (ws && ws_size >= needP){
    unsigned short* Apk = ws;
    unsigned short* Wpk = ws + APK_USHORTS;
    pack_fused<<<MB_CNT * NKT + 64 * NKT, 256, 0, stream>>>(X, W, Apk, Wpk);
    rbf_gemm_d<<<8192, 256, 0, stream>>>(Apk, Wpk, b, out);
  } else {
    rbf_gemm_nows<<<8192, 256, 0, stream>>>(X, W, b, out);
  }
}